// Round 4
// baseline (39.378 us; speedup 1.0000x reference)
//
#include <hip/hip_runtime.h>
#include <math.h>

#define THREADS 256

__device__ __forceinline__ float prcp(float x) { return __builtin_amdgcn_rcpf(x); }

__global__ void __launch_bounds__(THREADS, 1) iou3d_kernel(
    const float* __restrict__ pred, const float* __restrict__ tgt,
    const float* __restrict__ wgt, float* __restrict__ partial, int N) {
    int n = blockIdx.x * THREADS + threadIdx.x;
    float loss = 0.0f;
    if (n < N) {
        float p[7], t[7];
#pragma unroll
        for (int k = 0; k < 7; k++) {
            p[k] = pred[(size_t)n * 7 + k];
            float tv = tgt[(size_t)n * 7 + k];
            t[k] = (tv != tv) ? p[k] : tv;
        }
        // ---- corners ----
        const float txc[4] = {0.5f, -0.5f, -0.5f, 0.5f};
        const float tyc[4] = {0.5f, 0.5f, -0.5f, -0.5f};
        float s1, c1, s2, c2;
        __sincosf(p[6], &s1, &c1);
        __sincosf(t[6], &s2, &c2);
        float c1x[4], c1y[4], c2x[4], c2y[4];
#pragma unroll
        for (int k = 0; k < 4; k++) {
            float xo = p[3] * txc[k], yo = p[4] * tyc[k];
            c1x[k] = p[0] + c1 * xo - s1 * yo;
            c1y[k] = p[1] + s1 * xo + c1 * yo;
            xo = t[3] * txc[k]; yo = t[4] * tyc[k];
            c2x[k] = t[0] + c2 * xo - s2 * yo;
            c2y[k] = t[1] + s2 * xo + c2 * yo;
        }

        float vx[24], vy[24];
        unsigned vm = 0;
#pragma unroll
        for (int k = 0; k < 4; k++) { vx[k] = c1x[k]; vy[k] = c1y[k]; }
#pragma unroll
        for (int k = 0; k < 4; k++) { vx[4 + k] = c2x[k]; vy[4 + k] = c2y[k]; }

        // ---- corners-in-box (division-free: norms are > 0) ----
        {
            float abx = c2x[1] - c2x[0], aby = c2y[1] - c2y[0];
            float adx = c2x[3] - c2x[0], ady = c2y[3] - c2y[0];
            float nab = abx * abx + aby * aby, nad = adx * adx + ady * ady;
            float eab = 1e-6f * nab, ead = 1e-6f * nad;
#pragma unroll
            for (int k = 0; k < 4; k++) {
                float amx = c1x[k] - c2x[0], amy = c1y[k] - c2y[0];
                float pab = abx * amx + aby * amy;
                float pad = adx * amx + ady * amy;
                bool c = (pab > -eab) && (pab < nab + eab) &&
                         (pad > -ead) && (pad < nad + ead);
                vm |= ((unsigned)c) << k;
            }
        }
        {
            float abx = c1x[1] - c1x[0], aby = c1y[1] - c1y[0];
            float adx = c1x[3] - c1x[0], ady = c1y[3] - c1y[0];
            float nab = abx * abx + aby * aby, nad = adx * adx + ady * ady;
            float eab = 1e-6f * nab, ead = 1e-6f * nad;
#pragma unroll
            for (int k = 0; k < 4; k++) {
                float amx = c2x[k] - c1x[0], amy = c2y[k] - c1y[0];
                float pab = abx * amx + aby * amy;
                float pad = adx * amx + ady * amy;
                bool c = (pab > -eab) && (pab < nab + eab) &&
                         (pad > -ead) && (pad < nad + ead);
                vm |= ((unsigned)c) << (4 + k);
            }
        }

        // ---- 16 edge-edge tests, EXACT reference semantics (incl. its u-sign quirk) ----
#pragma unroll
        for (int e1 = 0; e1 < 4; e1++) {
            float x1 = c1x[e1], y1 = c1y[e1];
            float e1xv = c1x[(e1 + 1) & 3] - x1, e1yv = c1y[(e1 + 1) & 3] - y1;
#pragma unroll
            for (int e2 = 0; e2 < 4; e2++) {
                float x3 = c2x[e2], y3 = c2y[e2];
                float e2xv = c2x[(e2 + 1) & 3] - x3, e2yv = c2y[(e2 + 1) & 3] - y3;
                float num = e2yv * e1xv - e2xv * e1yv;
                float dx = x1 - x3, dy = y1 - y3;
                float den_t = e2xv * dy - e2yv * dx;
                float den_u = e1xv * dy - e1yv * dx;
                float r = prcp(num);
                float tt = den_t * r;
                float uu = -den_u * r;
                bool mk = (tt > 0.0f) && (tt < 1.0f) && (uu > 0.0f) && (uu < 1.0f);
                int idx = 8 + e1 * 4 + e2;
                vx[idx] = mk ? x1 + tt * e1xv : 0.0f;
                vy[idx] = mk ? y1 + tt * e1yv : 0.0f;
                vm |= ((unsigned)mk) << idx;
            }
        }

        // ---- centroid of valid vertices ----
        float sx = 0.0f, sy = 0.0f;
        int nv = __popc(vm);
#pragma unroll
        for (int k = 0; k < 24; k++) {
            bool v = (vm >> k) & 1u;
            sx += v ? vx[k] : 0.0f;
            sy += v ? vy[k] : 0.0f;
        }
        float den = fmaxf((float)nv, 1.0f);
        float r0 = prcp(den);
        float mx = sx * r0, my = sy * r0;

        // ---- sort keys: monotone pseudo-angle (order-equivalent to atan2) ----
        float ka[24], rx[24], ry[24];
#pragma unroll
        for (int k = 0; k < 24; k++) {
            float x = vx[k] - mx, y = vy[k] - my;
            rx[k] = x; ry[k] = y;
            float d = fabsf(x) + fabsf(y);
            float q = 1.0f - x * prcp(d);
            float pa = copysignf(q, y);
            pa = (d == 0.0f) ? 0.0f : pa;
            bool v = (vm >> k) & 1u;
            ka[k] = v ? pa : 1e6f;
        }

        // ---- Batcher odd-even mergesort network, n=24 (132 CEs), branchless ----
#define CE(A, B) do { \
        bool sw = ka[B] < ka[A]; \
        float ta = sw ? ka[B] : ka[A]; float tb = sw ? ka[A] : ka[B]; ka[A] = ta; ka[B] = tb; \
        ta = sw ? rx[B] : rx[A]; tb = sw ? rx[A] : rx[B]; rx[A] = ta; rx[B] = tb; \
        ta = sw ? ry[B] : ry[A]; tb = sw ? ry[A] : ry[B]; ry[A] = ta; ry[B] = tb; \
    } while (0)

        // p=1
        CE(0,1); CE(2,3); CE(4,5); CE(6,7); CE(8,9); CE(10,11); CE(12,13); CE(14,15); CE(16,17); CE(18,19); CE(20,21); CE(22,23);
        // p=2
        CE(0,2); CE(1,3); CE(4,6); CE(5,7); CE(8,10); CE(9,11); CE(12,14); CE(13,15); CE(16,18); CE(17,19); CE(20,22); CE(21,23);
        CE(1,2); CE(5,6); CE(9,10); CE(13,14); CE(17,18); CE(21,22);
        // p=4
        CE(0,4); CE(1,5); CE(2,6); CE(3,7); CE(8,12); CE(9,13); CE(10,14); CE(11,15); CE(16,20); CE(17,21); CE(18,22); CE(19,23);
        CE(2,4); CE(3,5); CE(10,12); CE(11,13); CE(18,20); CE(19,21);
        CE(1,2); CE(3,4); CE(5,6); CE(9,10); CE(11,12); CE(13,14); CE(17,18); CE(19,20); CE(21,22);
        // p=8
        CE(0,8); CE(1,9); CE(2,10); CE(3,11); CE(4,12); CE(5,13); CE(6,14); CE(7,15);
        CE(4,8); CE(5,9); CE(6,10); CE(7,11);
        CE(2,4); CE(3,5); CE(6,8); CE(7,9); CE(10,12); CE(11,13); CE(18,20); CE(19,21);
        CE(1,2); CE(3,4); CE(5,6); CE(7,8); CE(9,10); CE(11,12); CE(13,14); CE(17,18); CE(19,20); CE(21,22);
        // p=16
        CE(0,16); CE(1,17); CE(2,18); CE(3,19); CE(4,20); CE(5,21); CE(6,22); CE(7,23);
        CE(8,16); CE(9,17); CE(10,18); CE(11,19); CE(12,20); CE(13,21); CE(14,22); CE(15,23);
        CE(4,8); CE(5,9); CE(6,10); CE(7,11); CE(12,16); CE(13,17); CE(14,18); CE(15,19);
        CE(2,4); CE(3,5); CE(6,8); CE(7,9); CE(10,12); CE(11,13); CE(14,16); CE(15,17); CE(18,20); CE(19,21);
        CE(1,2); CE(3,4); CE(5,6); CE(7,8); CE(9,10); CE(11,12); CE(13,14); CE(15,16); CE(17,18); CE(19,20); CE(21,22);
#undef CE

        // ---- shoelace over the first nv sorted vertices (rel coords; telescoping-equivalent) ----
        float area2 = 0.0f;
#pragma unroll
        for (int i = 0; i + 1 < 24; i++) {
            float c = rx[i] * ry[i + 1] - rx[i + 1] * ry[i];
            area2 += (i + 1 < nv) ? c : 0.0f;
        }
        float lx = rx[0], ly = ry[0];
#pragma unroll
        for (int i = 1; i < 24; i++) {
            bool c = i < nv;
            lx = c ? rx[i] : lx;
            ly = c ? ry[i] : ly;
        }
        area2 += lx * ry[0] - rx[0] * ly;
        float inter2d = 0.5f * fabsf(area2);

        // ---- z overlap, volumes, iou ----
        float zmax1 = p[2] + p[5] * 0.5f, zmin1 = p[2] - p[5] * 0.5f;
        float zmax2 = t[2] + t[5] * 0.5f, zmin2 = t[2] - t[5] * 0.5f;
        float zov = fmaxf(fminf(zmax1, zmax2) - fmaxf(zmin1, zmin2), 0.0f);
        float inter3d = inter2d * zov;
        float v1 = p[3] * p[4] * p[5];
        float v2 = t[3] * t[4] * t[5];
        float uni = v1 + v2 - inter3d;
        float iou = inter3d / uni;
        loss = (1.0f - iou) * wgt[n];
    }

    // deterministic block reduction
#pragma unroll
    for (int off = 32; off > 0; off >>= 1) loss += __shfl_down(loss, off, 64);
    __shared__ float sm[THREADS / 64];
    int lane = threadIdx.x & 63, wv = threadIdx.x >> 6;
    if (lane == 0) sm[wv] = loss;
    __syncthreads();
    if (threadIdx.x == 0) {
        float s = 0.0f;
#pragma unroll
        for (int w = 0; w < THREADS / 64; w++) s += sm[w];
        partial[blockIdx.x] = s;
    }
}

__global__ void __launch_bounds__(256) reduce_kernel(const float* __restrict__ partial,
                                                     int nb, float* __restrict__ out, int N) {
    __shared__ float sm[256];
    float s = 0.0f;
    for (int i = threadIdx.x; i < nb; i += 256) s += partial[i];
    sm[threadIdx.x] = s;
    __syncthreads();
    for (int off = 128; off > 0; off >>= 1) {
        if (threadIdx.x < off) sm[threadIdx.x] += sm[threadIdx.x + off];
        __syncthreads();
    }
    if (threadIdx.x == 0) out[0] = sm[0] / (float)N;
}

extern "C" void kernel_launch(void* const* d_in, const int* in_sizes, int n_in,
                              void* d_out, int out_size, void* d_ws, size_t ws_size,
                              hipStream_t stream) {
    const float* pred = (const float*)d_in[0];
    const float* tgt  = (const float*)d_in[1];
    const float* wgt  = (const float*)d_in[2];
    int N = in_sizes[2];
    int nb = (N + THREADS - 1) / THREADS;
    float* partial = (float*)d_ws;
    iou3d_kernel<<<nb, THREADS, 0, stream>>>(pred, tgt, wgt, partial, N);
    reduce_kernel<<<1, 256, 0, stream>>>(partial, nb, (float*)d_out, N);
}

// Round 5
// 33.048 us; speedup vs baseline: 1.1915x; 1.1915x over previous
//
#include <hip/hip_runtime.h>
#include <hip/hip_fp16.h>
#include <math.h>

#define THREADS 256
#define VSTRIDE 25   // LDS u32 words per thread (odd => conflict-free banks)

__device__ __forceinline__ float prcp(float x) { return __builtin_amdgcn_rcpf(x); }

__device__ __forceinline__ unsigned packh2(float x, float y) {
    __half2 h = __floats2half2_rn(x, y);
    return *reinterpret_cast<unsigned*>(&h);
}
__device__ __forceinline__ void unpackh2(unsigned u, float& x, float& y) {
    __half2 h = *reinterpret_cast<__half2*>(&u);
    x = __low2float(h); y = __high2float(h);
}

__global__ void __launch_bounds__(THREADS) iou3d_kernel(
    const float* __restrict__ pred, const float* __restrict__ tgt,
    const float* __restrict__ wgt, float* __restrict__ partial, int N) {
    __shared__ unsigned ldsbuf[THREADS * VSTRIDE];
    int tid = threadIdx.x;
    unsigned* myv = &ldsbuf[tid * VSTRIDE];
    int n = blockIdx.x * THREADS + tid;
    float loss = 0.0f;
    if (n < N) {
        float p[7], t[7];
#pragma unroll
        for (int k = 0; k < 7; k++) {
            p[k] = pred[(size_t)n * 7 + k];
            float tv = tgt[(size_t)n * 7 + k];
            t[k] = (tv != tv) ? p[k] : tv;
        }
        // z-overlap & volumes early (frees p[2],p[5],t[2],t[5])
        float zmax1 = p[2] + p[5] * 0.5f, zmin1 = p[2] - p[5] * 0.5f;
        float zmax2 = t[2] + t[5] * 0.5f, zmin2 = t[2] - t[5] * 0.5f;
        float zov = fmaxf(fminf(zmax1, zmax2) - fmaxf(zmin1, zmin2), 0.0f);
        float vol1 = p[3] * p[4] * p[5], vol2 = t[3] * t[4] * t[5];

        const float txc[4] = {0.5f, -0.5f, -0.5f, 0.5f};
        const float tyc[4] = {0.5f, 0.5f, -0.5f, -0.5f};
        float s1, c1, s2, c2;
        __sincosf(p[6], &s1, &c1);
        __sincosf(t[6], &s2, &c2);
        float ox = t[0] - p[0], oy = t[1] - p[1];
        // corners in box1-centered frame (translation only; shoelace invariant)
        float c1x[4], c1y[4], c2x[4], c2y[4];
#pragma unroll
        for (int k = 0; k < 4; k++) {
            float xo = p[3] * txc[k], yo = p[4] * tyc[k];
            c1x[k] = c1 * xo - s1 * yo;
            c1y[k] = s1 * xo + c1 * yo;
            xo = t[3] * txc[k]; yo = t[4] * tyc[k];
            c2x[k] = ox + c2 * xo - s2 * yo;
            c2y[k] = oy + s2 * xo + c2 * yo;
        }
        unsigned vm = 0;
        // corners-in-box tests (division-free)
        {
            float abx = c2x[1] - c2x[0], aby = c2y[1] - c2y[0];
            float adx = c2x[3] - c2x[0], ady = c2y[3] - c2y[0];
            float nab = abx * abx + aby * aby, nad = adx * adx + ady * ady;
            float eab = 1e-6f * nab, ead = 1e-6f * nad;
#pragma unroll
            for (int k = 0; k < 4; k++) {
                float amx = c1x[k] - c2x[0], amy = c1y[k] - c2y[0];
                float pab = abx * amx + aby * amy, pad = adx * amx + ady * amy;
                bool c = (pab > -eab) && (pab < nab + eab) &&
                         (pad > -ead) && (pad < nad + ead);
                vm |= ((unsigned)c) << k;
            }
        }
        {
            float abx = c1x[1] - c1x[0], aby = c1y[1] - c1y[0];
            float adx = c1x[3] - c1x[0], ady = c1y[3] - c1y[0];
            float nab = abx * abx + aby * aby, nad = adx * adx + ady * ady;
            float eab = 1e-6f * nab, ead = 1e-6f * nad;
#pragma unroll
            for (int k = 0; k < 4; k++) {
                float amx = c2x[k] - c1x[0], amy = c2y[k] - c1y[0];
                float pab = abx * amx + aby * amy, pad = adx * amx + ady * amy;
                bool c = (pab > -eab) && (pab < nab + eab) &&
                         (pad > -ead) && (pad < nad + ead);
                vm |= ((unsigned)c) << (4 + k);
            }
        }
        // store corners to LDS (f16x2) + centroid accumulation (f32, masked)
        float sx = 0.0f, sy = 0.0f;
#pragma unroll
        for (int k = 0; k < 4; k++) {
            myv[k] = packh2(c1x[k], c1y[k]);
            bool v = (vm >> k) & 1u;
            sx += v ? c1x[k] : 0.0f; sy += v ? c1y[k] : 0.0f;
        }
#pragma unroll
        for (int k = 0; k < 4; k++) {
            myv[4 + k] = packh2(c2x[k], c2y[k]);
            bool v = (vm >> (4 + k)) & 1u;
            sx += v ? c2x[k] : 0.0f; sy += v ? c2y[k] : 0.0f;
        }
        // 16 edge-edge tests, EXACT reference semantics (incl. the u-sign quirk)
#pragma unroll
        for (int e1 = 0; e1 < 4; e1++) {
            float x1 = c1x[e1], y1 = c1y[e1];
            float e1xv = c1x[(e1 + 1) & 3] - x1, e1yv = c1y[(e1 + 1) & 3] - y1;
#pragma unroll
            for (int e2 = 0; e2 < 4; e2++) {
                float x3 = c2x[e2], y3 = c2y[e2];
                float e2xv = c2x[(e2 + 1) & 3] - x3, e2yv = c2y[(e2 + 1) & 3] - y3;
                float num = e2yv * e1xv - e2xv * e1yv;
                float dx = x1 - x3, dy = y1 - y3;
                float den_t = e2xv * dy - e2yv * dx;
                float den_u = e1xv * dy - e1yv * dx;
                float r = prcp(num);
                float tt = den_t * r;
                float uu = -den_u * r;
                bool mk = (tt > 0.0f) && (tt < 1.0f) && (uu > 0.0f) && (uu < 1.0f);
                float px = mk ? x1 + tt * e1xv : 0.0f;
                float py = mk ? y1 + tt * e1yv : 0.0f;
                int idx = 8 + e1 * 4 + e2;
                myv[idx] = packh2(px, py);
                vm |= ((unsigned)mk) << idx;
                sx += px; sy += py;   // invalid already zeroed (matches ref)
            }
        }

        int nv = __popc(vm);
        float r0 = prcp(fmaxf((float)nv, 1.0f));
        float mx = sx * r0, my = sy * r0;

        // sort keys: monotone-mapped pseudo-angle bits | vertex index (stable)
        unsigned ka[24];
        const unsigned SENTK = 0xC9742400u & 0xFFFFFFE0u;  // mono(1e6), low5 cleared
#pragma unroll
        for (int k = 0; k < 24; k++) {
            float x, y;
            unpackh2(myv[k], x, y);
            x -= mx; y -= my;
            float d = fabsf(x) + fabsf(y);
            float q = 1.0f - x * prcp(d);
            float pa = copysignf(q, y);
            pa = (d == 0.0f) ? 0.0f : pa;
            unsigned b = __float_as_uint(pa);
            unsigned mono = b ^ ((unsigned)((int)b >> 31) | 0x80000000u);
            unsigned key = (mono & 0xFFFFFFE0u) | (unsigned)k;
            bool v = (vm >> k) & 1u;
            ka[k] = v ? key : (SENTK | (unsigned)k);
        }

        // Batcher odd-even mergesort, n=24 (132 CEs), 2 ops each
#define CE(A, B) { unsigned lo_ = ka[A] < ka[B] ? ka[A] : ka[B]; \
                   unsigned hi_ = ka[A] < ka[B] ? ka[B] : ka[A]; \
                   ka[A] = lo_; ka[B] = hi_; }
        CE(0,1); CE(2,3); CE(4,5); CE(6,7); CE(8,9); CE(10,11); CE(12,13); CE(14,15); CE(16,17); CE(18,19); CE(20,21); CE(22,23);
        CE(0,2); CE(1,3); CE(4,6); CE(5,7); CE(8,10); CE(9,11); CE(12,14); CE(13,15); CE(16,18); CE(17,19); CE(20,22); CE(21,23);
        CE(1,2); CE(5,6); CE(9,10); CE(13,14); CE(17,18); CE(21,22);
        CE(0,4); CE(1,5); CE(2,6); CE(3,7); CE(8,12); CE(9,13); CE(10,14); CE(11,15); CE(16,20); CE(17,21); CE(18,22); CE(19,23);
        CE(2,4); CE(3,5); CE(10,12); CE(11,13); CE(18,20); CE(19,21);
        CE(1,2); CE(3,4); CE(5,6); CE(9,10); CE(11,12); CE(13,14); CE(17,18); CE(19,20); CE(21,22);
        CE(0,8); CE(1,9); CE(2,10); CE(3,11); CE(4,12); CE(5,13); CE(6,14); CE(7,15);
        CE(4,8); CE(5,9); CE(6,10); CE(7,11);
        CE(2,4); CE(3,5); CE(6,8); CE(7,9); CE(10,12); CE(11,13); CE(18,20); CE(19,21);
        CE(1,2); CE(3,4); CE(5,6); CE(7,8); CE(9,10); CE(11,12); CE(13,14); CE(17,18); CE(19,20); CE(21,22);
        CE(0,16); CE(1,17); CE(2,18); CE(3,19); CE(4,20); CE(5,21); CE(6,22); CE(7,23);
        CE(8,16); CE(9,17); CE(10,18); CE(11,19); CE(12,20); CE(13,21); CE(14,22); CE(15,23);
        CE(4,8); CE(5,9); CE(6,10); CE(7,11); CE(12,16); CE(13,17); CE(14,18); CE(15,19);
        CE(2,4); CE(3,5); CE(6,8); CE(7,9); CE(10,12); CE(11,13); CE(14,16); CE(15,17); CE(18,20); CE(19,21);
        CE(1,2); CE(3,4); CE(5,6); CE(7,8); CE(9,10); CE(11,12); CE(13,14); CE(15,16); CE(17,18); CE(19,20); CE(21,22);
#undef CE

        // gather sorted vertices (runtime idx -> LDS), then ref-exact cyclic shoelace:
        // poly_i = (i < nv) ? g_i : g_0 ; area2 = sum_i cross(poly_i, poly_{(i+1)%24})
        unsigned gu[24];
#pragma unroll
        for (int i = 0; i < 24; i++) gu[i] = myv[ka[i] & 31u];
        float g0x, g0y;
        unpackh2(gu[0], g0x, g0y);
        float prevx = g0x, prevy = g0y;   // poly_0 == g_0 for any nv
        float area2 = 0.0f;
#pragma unroll
        for (int i = 1; i < 24; i++) {
            float xx, yy;
            unpackh2(gu[i], xx, yy);
            bool c = i < nv;
            float cxv = c ? xx : g0x;
            float cyv = c ? yy : g0y;
            area2 += prevx * cyv - cxv * prevy;
            prevx = cxv; prevy = cyv;
        }
        area2 += prevx * g0y - g0x * prevy;  // wrap to poly_0
        float inter2d = 0.5f * fabsf(area2);

        float inter3d = inter2d * zov;
        float uni = vol1 + vol2 - inter3d;
        float iou = inter3d / uni;
        loss = (1.0f - iou) * wgt[n];
    }

    // deterministic block reduction
#pragma unroll
    for (int off = 32; off > 0; off >>= 1) loss += __shfl_down(loss, off, 64);
    __shared__ float sm[THREADS / 64];
    int lane = threadIdx.x & 63, wv = threadIdx.x >> 6;
    if (lane == 0) sm[wv] = loss;
    __syncthreads();
    if (threadIdx.x == 0) {
        float s = 0.0f;
#pragma unroll
        for (int w = 0; w < THREADS / 64; w++) s += sm[w];
        partial[blockIdx.x] = s;
    }
}

__global__ void __launch_bounds__(256) reduce_kernel(const float* __restrict__ partial,
                                                     int nb, float* __restrict__ out, int N) {
    __shared__ float sm[256];
    float s = 0.0f;
    for (int i = threadIdx.x; i < nb; i += 256) s += partial[i];
    sm[threadIdx.x] = s;
    __syncthreads();
    for (int off = 128; off > 0; off >>= 1) {
        if (threadIdx.x < off) sm[threadIdx.x] += sm[threadIdx.x + off];
        __syncthreads();
    }
    if (threadIdx.x == 0) out[0] = sm[0] / (float)N;
}

extern "C" void kernel_launch(void* const* d_in, const int* in_sizes, int n_in,
                              void* d_out, int out_size, void* d_ws, size_t ws_size,
                              hipStream_t stream) {
    const float* pred = (const float*)d_in[0];
    const float* tgt  = (const float*)d_in[1];
    const float* wgt  = (const float*)d_in[2];
    int N = in_sizes[2];
    int nb = (N + THREADS - 1) / THREADS;
    float* partial = (float*)d_ws;
    iou3d_kernel<<<nb, THREADS, 0, stream>>>(pred, tgt, wgt, partial, N);
    reduce_kernel<<<1, 256, 0, stream>>>(partial, nb, (float*)d_out, N);
}

// Round 6
// 28.761 us; speedup vs baseline: 1.3691x; 1.1491x over previous
//
#include <hip/hip_runtime.h>
#include <hip/hip_fp16.h>
#include <math.h>

#define THREADS 64
#define VSTRIDE 25   // odd word stride per thread -> conflict-free LDS banks

__device__ __forceinline__ float prcp(float x) { return __builtin_amdgcn_rcpf(x); }

__device__ __forceinline__ unsigned packh2(float x, float y) {
    __half2 h = __floats2half2_rn(x, y);
    return *reinterpret_cast<unsigned*>(&h);
}
__device__ __forceinline__ void unpackh2(unsigned u, float& x, float& y) {
    __half2 h = *reinterpret_cast<__half2*>(&u);
    x = __low2float(h); y = __high2float(h);
}

__global__ void __launch_bounds__(THREADS) iou3d_kernel(
    const float* __restrict__ pred, const float* __restrict__ tgt,
    const float* __restrict__ wgt, float* __restrict__ partial, int N) {
    __shared__ unsigned ldsbuf[THREADS * VSTRIDE];
    int tid = threadIdx.x;
    unsigned* myv = &ldsbuf[tid * VSTRIDE];
    int n = blockIdx.x * THREADS + tid;
    float loss = 0.0f;
    if (n < N) {
        float p[7], t[7];
#pragma unroll
        for (int k = 0; k < 7; k++) {
            p[k] = pred[(size_t)n * 7 + k];
            float tv = tgt[(size_t)n * 7 + k];
            t[k] = (tv != tv) ? p[k] : tv;
        }
        float w = wgt[n];
        float zmax1 = p[2] + p[5] * 0.5f, zmin1 = p[2] - p[5] * 0.5f;
        float zmax2 = t[2] + t[5] * 0.5f, zmin2 = t[2] - t[5] * 0.5f;
        float zov = fmaxf(fminf(zmax1, zmax2) - fmaxf(zmin1, zmin2), 0.0f);
        float vol1 = p[3] * p[4] * p[5], vol2 = t[3] * t[4] * t[5];

        float hw1 = 0.5f * p[3], hh1 = 0.5f * p[4];
        float hw2 = 0.5f * t[3], hh2 = 0.5f * t[4];
        float s1, c1v, s2, c2v;
        __sincosf(p[6], &s1, &c1v);
        __sincosf(t[6], &s2, &c2v);
        float c12 = c1v * c2v + s1 * s2;   // cos(a1-a2)
        float s12 = s1 * c2v - c1v * s2;   // sin(a1-a2)
        float ddx = p[0] - t[0], ddy = p[1] - t[1];
        // box1 center in frame2; box2 center in frame1
        float T12x =  c2v * ddx + s2 * ddy;
        float T12y = -s2 * ddx + c2v * ddy;
        float T21x = -(c1v * ddx + s1 * ddy);
        float T21y =  s1 * ddx - c1v * ddy;
        // box1 half-edge vectors in frame2
        float ux = c12 * hw1, uy = s12 * hw1;
        float wx = -s12 * hh1, wy = c12 * hh1;
        // box1 corners in frame2 (ring matches reference corner order)
        float fx[4], fy[4];
        fx[0] = T12x + ux + wx; fy[0] = T12y + uy + wy;
        fx[1] = T12x - ux + wx; fy[1] = T12y - uy + wy;
        fx[2] = T12x - ux - wx; fy[2] = T12y - uy - wy;
        fx[3] = T12x + ux - wx; fy[3] = T12y + uy - wy;

        unsigned vm = 0;
        // box1 corners in box2: |x|<hw2(1+2eps), |y|<hh2(1+2eps)
        float bx2 = hw2 * (1.0f + 2e-6f), by2 = hh2 * (1.0f + 2e-6f);
#pragma unroll
        for (int k = 0; k < 4; k++) {
            bool c = (fabsf(fx[k]) < bx2) && (fabsf(fy[k]) < by2);
            vm |= ((unsigned)c) << k;
        }
        // box2 corners in box1 (frame1)
        float u2x = c12 * hw2, u2y = -s12 * hw2;
        float v2x = s12 * hh2, v2y = c12 * hh2;
        float bx1 = hw1 * (1.0f + 2e-6f), by1 = hh1 * (1.0f + 2e-6f);
        {
            float qx, qy;
            qx = T21x + u2x + v2x; qy = T21y + u2y + v2y;
            vm |= ((unsigned)((fabsf(qx) < bx1) && (fabsf(qy) < by1))) << 4;
            qx = T21x - u2x + v2x; qy = T21y - u2y + v2y;
            vm |= ((unsigned)((fabsf(qx) < bx1) && (fabsf(qy) < by1))) << 5;
            qx = T21x - u2x - v2x; qy = T21y - u2y - v2y;
            vm |= ((unsigned)((fabsf(qx) < bx1) && (fabsf(qy) < by1))) << 6;
            qx = T21x + u2x - v2x; qy = T21y + u2y - v2y;
            vm |= ((unsigned)((fabsf(qx) < bx1) && (fabsf(qy) < by1))) << 7;
        }
        // store corners + masked centroid sums
        float sx = 0.0f, sy = 0.0f;
#pragma unroll
        for (int k = 0; k < 4; k++) {
            myv[k] = packh2(fx[k], fy[k]);
            bool v = (vm >> k) & 1u;
            sx += v ? fx[k] : 0.0f; sy += v ? fy[k] : 0.0f;
        }
        myv[4] = packh2(hw2, hh2);  myv[5] = packh2(-hw2, hh2);
        myv[6] = packh2(-hw2, -hh2); myv[7] = packh2(hw2, -hh2);
        {
            bool v4 = (vm >> 4) & 1u, v5 = (vm >> 5) & 1u, v6 = (vm >> 6) & 1u, v7 = (vm >> 7) & 1u;
            sx += (v4 ? hw2 : 0.0f) + (v5 ? -hw2 : 0.0f) + (v6 ? -hw2 : 0.0f) + (v7 ? hw2 : 0.0f);
            sy += (v4 ? hh2 : 0.0f) + (v5 ? hh2 : 0.0f) + (v6 ? -hh2 : 0.0f) + (v7 ? -hh2 : 0.0f);
        }

        // edge vectors of box1 (±2u, ±2w) and shared reciprocals
        float tux = ux + ux, tuy = uy + uy, twx = wx + wx, twy = wy + wy;
        float rtux = prcp(tux), rtuy = prcp(tuy), rtwx = prcp(twx), rtwy = prcp(twy);
        float dxe[4] = {-tux, -twx, tux, twx};
        float dye[4] = {-tuy, -twy, tuy, twy};
        float rdxe[4] = {-rtux, -rtwx, rtux, rtwx};
        float rdye[4] = {-rtuy, -rtwy, rtuy, rtwy};
        float r2w = prcp(hw2 + hw2), r2h = prcp(hh2 + hh2);

        // 16 intersections; exact reference semantics (incl. u-sign quirk), simplified in frame2.
        // box2 ring edges: e2=0 horiz Y=+hh2 (x3=+hw2, rDX=-r2w); e2=1 vert X=-hw2 (y3=+hh2, rDY=-r2h);
        //                  e2=2 horiz Y=-hh2 (x3=-hw2, rDX=+r2w); e2=3 vert X=+hw2 (y3=-hh2, rDY=+r2h)
        float pvar[16];  // the single varying coordinate of each intersection vertex
#pragma unroll
        for (int e1 = 0; e1 < 4; e1++) {
            float x1 = fx[e1], y1 = fy[e1];
            {   // e2 = 0
                float tt = (hh2 - y1) * rdye[e1];
                float px = fmaf(tt, dxe[e1], x1);
                float uu = (hw2 - px) * (-r2w);
                bool mk = (tt > 0.0f) && (tt < 1.0f) && (uu > 0.0f) && (uu < 1.0f);
                pvar[e1 * 4 + 0] = px;
                float pxm = mk ? px : 0.0f, pym = mk ? hh2 : 0.0f;
                myv[8 + e1 * 4 + 0] = packh2(pxm, pym);
                sx += pxm; sy += pym;
                vm |= ((unsigned)mk) << (8 + e1 * 4 + 0);
            }
            {   // e2 = 1
                float tt = (-hw2 - x1) * rdxe[e1];
                float py = fmaf(tt, dye[e1], y1);
                float uu = (hh2 - py) * (-r2h);
                bool mk = (tt > 0.0f) && (tt < 1.0f) && (uu > 0.0f) && (uu < 1.0f);
                pvar[e1 * 4 + 1] = py;
                float pxm = mk ? -hw2 : 0.0f, pym = mk ? py : 0.0f;
                myv[8 + e1 * 4 + 1] = packh2(pxm, pym);
                sx += pxm; sy += pym;
                vm |= ((unsigned)mk) << (8 + e1 * 4 + 1);
            }
            {   // e2 = 2
                float tt = (-hh2 - y1) * rdye[e1];
                float px = fmaf(tt, dxe[e1], x1);
                float uu = (-hw2 - px) * r2w;
                bool mk = (tt > 0.0f) && (tt < 1.0f) && (uu > 0.0f) && (uu < 1.0f);
                pvar[e1 * 4 + 2] = px;
                float pxm = mk ? px : 0.0f, pym = mk ? -hh2 : 0.0f;
                myv[8 + e1 * 4 + 2] = packh2(pxm, pym);
                sx += pxm; sy += pym;
                vm |= ((unsigned)mk) << (8 + e1 * 4 + 2);
            }
            {   // e2 = 3
                float tt = (hw2 - x1) * rdxe[e1];
                float py = fmaf(tt, dye[e1], y1);
                float uu = (-hh2 - py) * r2h;
                bool mk = (tt > 0.0f) && (tt < 1.0f) && (uu > 0.0f) && (uu < 1.0f);
                pvar[e1 * 4 + 3] = py;
                float pxm = mk ? hw2 : 0.0f, pym = mk ? py : 0.0f;
                myv[8 + e1 * 4 + 3] = packh2(pxm, pym);
                sx += pxm; sy += pym;
                vm |= ((unsigned)mk) << (8 + e1 * 4 + 3);
            }
        }

        int nv = __popc(vm);
        float r0 = prcp(fmaxf((float)nv, 1.0f));
        float mx = sx * r0, my = sy * r0;

        // keys from REGISTER coords: diamond pseudo-angle + 4 (positive -> bits monotone), idx in low 5
        unsigned ka[24];
#define MKKEY(K, XR, YR) do { \
        float xr_ = (XR), yr_ = (YR); \
        float d_ = fabsf(xr_) + fabsf(yr_); \
        float q_ = 1.0f - xr_ * prcp(d_); \
        float pa_ = copysignf(q_, yr_) + 4.0f; \
        unsigned key_ = (__float_as_uint(pa_) & 0xFFFFFFE0u) | (unsigned)(K); \
        ka[K] = ((vm >> (K)) & 1u) ? key_ : (0x7F000000u | (unsigned)(K)); \
    } while (0)
        float hpx = hw2 - mx, hmx = -hw2 - mx, hpy = hh2 - my, hmy = -hh2 - my;
#pragma unroll
        for (int k = 0; k < 4; k++) MKKEY(k, fx[k] - mx, fy[k] - my);
        MKKEY(4, hpx, hpy); MKKEY(5, hmx, hpy); MKKEY(6, hmx, hmy); MKKEY(7, hpx, hmy);
#pragma unroll
        for (int e1 = 0; e1 < 4; e1++) {
            MKKEY(8 + e1 * 4 + 0, pvar[e1 * 4 + 0] - mx, hpy);
            MKKEY(8 + e1 * 4 + 1, hmx, pvar[e1 * 4 + 1] - my);
            MKKEY(8 + e1 * 4 + 2, pvar[e1 * 4 + 2] - mx, hmy);
            MKKEY(8 + e1 * 4 + 3, hpx, pvar[e1 * 4 + 3] - my);
        }
#undef MKKEY

        // Batcher odd-even mergesort, n=24 (132 CEs), u32 min/max
#define CE(A, B) { unsigned lo_ = ka[A] < ka[B] ? ka[A] : ka[B]; \
                   unsigned hi_ = ka[A] < ka[B] ? ka[B] : ka[A]; \
                   ka[A] = lo_; ka[B] = hi_; }
        CE(0,1); CE(2,3); CE(4,5); CE(6,7); CE(8,9); CE(10,11); CE(12,13); CE(14,15); CE(16,17); CE(18,19); CE(20,21); CE(22,23);
        CE(0,2); CE(1,3); CE(4,6); CE(5,7); CE(8,10); CE(9,11); CE(12,14); CE(13,15); CE(16,18); CE(17,19); CE(20,22); CE(21,23);
        CE(1,2); CE(5,6); CE(9,10); CE(13,14); CE(17,18); CE(21,22);
        CE(0,4); CE(1,5); CE(2,6); CE(3,7); CE(8,12); CE(9,13); CE(10,14); CE(11,15); CE(16,20); CE(17,21); CE(18,22); CE(19,23);
        CE(2,4); CE(3,5); CE(10,12); CE(11,13); CE(18,20); CE(19,21);
        CE(1,2); CE(3,4); CE(5,6); CE(9,10); CE(11,12); CE(13,14); CE(17,18); CE(19,20); CE(21,22);
        CE(0,8); CE(1,9); CE(2,10); CE(3,11); CE(4,12); CE(5,13); CE(6,14); CE(7,15);
        CE(4,8); CE(5,9); CE(6,10); CE(7,11);
        CE(2,4); CE(3,5); CE(6,8); CE(7,9); CE(10,12); CE(11,13); CE(18,20); CE(19,21);
        CE(1,2); CE(3,4); CE(5,6); CE(7,8); CE(9,10); CE(11,12); CE(13,14); CE(17,18); CE(19,20); CE(21,22);
        CE(0,16); CE(1,17); CE(2,18); CE(3,19); CE(4,20); CE(5,21); CE(6,22); CE(7,23);
        CE(8,16); CE(9,17); CE(10,18); CE(11,19); CE(12,20); CE(13,21); CE(14,22); CE(15,23);
        CE(4,8); CE(5,9); CE(6,10); CE(7,11); CE(12,16); CE(13,17); CE(14,18); CE(15,19);
        CE(2,4); CE(3,5); CE(6,8); CE(7,9); CE(10,12); CE(11,13); CE(14,16); CE(15,17); CE(18,20); CE(19,21);
        CE(1,2); CE(3,4); CE(5,6); CE(7,8); CE(9,10); CE(11,12); CE(13,14); CE(15,16); CE(17,18); CE(19,20); CE(21,22);
#undef CE

        // gather sorted vertices from LDS; ref-exact cyclic shoelace
        unsigned gu[24];
#pragma unroll
        for (int i = 0; i < 24; i++) gu[i] = myv[ka[i] & 31u];
        float g0x, g0y;
        unpackh2(gu[0], g0x, g0y);
        float prevx = g0x, prevy = g0y;
        float area2 = 0.0f;
#pragma unroll
        for (int i = 1; i < 24; i++) {
            float xx, yy;
            unpackh2(gu[i], xx, yy);
            bool c = i < nv;
            float cxv = c ? xx : g0x;
            float cyv = c ? yy : g0y;
            area2 += prevx * cyv - cxv * prevy;
            prevx = cxv; prevy = cyv;
        }
        area2 += prevx * g0y - g0x * prevy;
        float inter2d = 0.5f * fabsf(area2);

        float inter3d = inter2d * zov;
        float uni = vol1 + vol2 - inter3d;
        float iou = inter3d / uni;
        loss = (1.0f - iou) * w;
    }

    // one wave per block: pure shuffle reduction, no LDS/barrier
#pragma unroll
    for (int off = 32; off > 0; off >>= 1) loss += __shfl_down(loss, off, 64);
    if (threadIdx.x == 0) partial[blockIdx.x] = loss;
}

__global__ void __launch_bounds__(1024) reduce_kernel(const float* __restrict__ partial,
                                                      int nb, float* __restrict__ out, int N) {
    float s = 0.0f;
    for (int i = threadIdx.x; i < nb; i += 1024) s += partial[i];
#pragma unroll
    for (int off = 32; off > 0; off >>= 1) s += __shfl_down(s, off, 64);
    __shared__ float sm[16];
    int lane = threadIdx.x & 63, wv = threadIdx.x >> 6;
    if (lane == 0) sm[wv] = s;
    __syncthreads();
    if (threadIdx.x == 0) {
        float tot = 0.0f;
#pragma unroll
        for (int k = 0; k < 16; k++) tot += sm[k];
        out[0] = tot / (float)N;
    }
}

extern "C" void kernel_launch(void* const* d_in, const int* in_sizes, int n_in,
                              void* d_out, int out_size, void* d_ws, size_t ws_size,
                              hipStream_t stream) {
    const float* pred = (const float*)d_in[0];
    const float* tgt  = (const float*)d_in[1];
    const float* wgt  = (const float*)d_in[2];
    int N = in_sizes[2];
    int nb = (N + THREADS - 1) / THREADS;
    float* partial = (float*)d_ws;
    iou3d_kernel<<<nb, THREADS, 0, stream>>>(pred, tgt, wgt, partial, N);
    reduce_kernel<<<1, 1024, 0, stream>>>(partial, nb, (float*)d_out, N);
}

// Round 7
// 27.847 us; speedup vs baseline: 1.4141x; 1.0328x over previous
//
#include <hip/hip_runtime.h>
#include <hip/hip_fp16.h>
#include <math.h>

#define THREADS 128   // 2 waves/block; [24][128] u32 LDS = 12.3KB -> 13 blocks/CU -> 26 waves (81%)

__device__ __forceinline__ float prcp(float x) { return __builtin_amdgcn_rcpf(x); }

__device__ __forceinline__ unsigned packh2(float x, float y) {
    __half2 h = __floats2half2_rn(x, y);
    return *reinterpret_cast<unsigned*>(&h);
}
__device__ __forceinline__ void unpackh2(unsigned u, float& x, float& y) {
    __half2 h = *reinterpret_cast<__half2*>(&u);
    x = __low2float(h); y = __high2float(h);
}

__global__ void __launch_bounds__(THREADS) iou3d_kernel(
    const float* __restrict__ pred, const float* __restrict__ tgt,
    const float* __restrict__ wgt, float* __restrict__ partial, int N) {
    __shared__ unsigned ldsbuf[24 * THREADS];   // slot-major: bank = tid%32, conflict-free
    int tid = threadIdx.x;
#define LDSV(S) ldsbuf[((S) << 7) + tid]
    int n = blockIdx.x * THREADS + tid;
    float loss = 0.0f;
    if (n < N) {
        float p[7], t[7];
#pragma unroll
        for (int k = 0; k < 7; k++) {
            p[k] = pred[(size_t)n * 7 + k];
            float tv = tgt[(size_t)n * 7 + k];
            t[k] = (tv != tv) ? p[k] : tv;
        }
        float w = wgt[n];
        float zmax1 = p[2] + p[5] * 0.5f, zmin1 = p[2] - p[5] * 0.5f;
        float zmax2 = t[2] + t[5] * 0.5f, zmin2 = t[2] - t[5] * 0.5f;
        float zov = fmaxf(fminf(zmax1, zmax2) - fmaxf(zmin1, zmin2), 0.0f);
        float vol1 = p[3] * p[4] * p[5], vol2 = t[3] * t[4] * t[5];

        float hw1 = 0.5f * p[3], hh1 = 0.5f * p[4];
        float hw2 = 0.5f * t[3], hh2 = 0.5f * t[4];
        float s1, c1v, s2, c2v;
        __sincosf(p[6], &s1, &c1v);
        __sincosf(t[6], &s2, &c2v);
        float c12 = c1v * c2v + s1 * s2;   // cos(a1-a2)
        float s12 = s1 * c2v - c1v * s2;   // sin(a1-a2)
        float ddx = p[0] - t[0], ddy = p[1] - t[1];
        float T12x =  c2v * ddx + s2 * ddy;
        float T12y = -s2 * ddx + c2v * ddy;
        float T21x = -(c1v * ddx + s1 * ddy);
        float T21y =  s1 * ddx - c1v * ddy;
        float ux = c12 * hw1, uy = s12 * hw1;
        float wx = -s12 * hh1, wy = c12 * hh1;
        float fx[4], fy[4];
        fx[0] = T12x + ux + wx; fy[0] = T12y + uy + wy;
        fx[1] = T12x - ux + wx; fy[1] = T12y - uy + wy;
        fx[2] = T12x - ux - wx; fy[2] = T12y - uy - wy;
        fx[3] = T12x + ux - wx; fy[3] = T12y + uy - wy;

        unsigned vm = 0;
        float bx2 = hw2 * (1.0f + 2e-6f), by2 = hh2 * (1.0f + 2e-6f);
#pragma unroll
        for (int k = 0; k < 4; k++) {
            bool c = (fabsf(fx[k]) < bx2) && (fabsf(fy[k]) < by2);
            vm |= ((unsigned)c) << k;
        }
        float u2x = c12 * hw2, u2y = -s12 * hw2;
        float v2x = s12 * hh2, v2y = c12 * hh2;
        float bx1 = hw1 * (1.0f + 2e-6f), by1 = hh1 * (1.0f + 2e-6f);
        {
            float qx, qy;
            qx = T21x + u2x + v2x; qy = T21y + u2y + v2y;
            vm |= ((unsigned)((fabsf(qx) < bx1) && (fabsf(qy) < by1))) << 4;
            qx = T21x - u2x + v2x; qy = T21y - u2y + v2y;
            vm |= ((unsigned)((fabsf(qx) < bx1) && (fabsf(qy) < by1))) << 5;
            qx = T21x - u2x - v2x; qy = T21y - u2y - v2y;
            vm |= ((unsigned)((fabsf(qx) < bx1) && (fabsf(qy) < by1))) << 6;
            qx = T21x + u2x - v2x; qy = T21y + u2y - v2y;
            vm |= ((unsigned)((fabsf(qx) < bx1) && (fabsf(qy) < by1))) << 7;
        }
        float sx = 0.0f, sy = 0.0f;
#pragma unroll
        for (int k = 0; k < 4; k++) {
            LDSV(k) = packh2(fx[k], fy[k]);
            bool v = (vm >> k) & 1u;
            sx += v ? fx[k] : 0.0f; sy += v ? fy[k] : 0.0f;
        }
        LDSV(4) = packh2(hw2, hh2);   LDSV(5) = packh2(-hw2, hh2);
        LDSV(6) = packh2(-hw2, -hh2); LDSV(7) = packh2(hw2, -hh2);
        {
            bool v4 = (vm >> 4) & 1u, v5 = (vm >> 5) & 1u, v6 = (vm >> 6) & 1u, v7 = (vm >> 7) & 1u;
            sx += (v4 ? hw2 : 0.0f) + (v5 ? -hw2 : 0.0f) + (v6 ? -hw2 : 0.0f) + (v7 ? hw2 : 0.0f);
            sy += (v4 ? hh2 : 0.0f) + (v5 ? hh2 : 0.0f) + (v6 ? -hh2 : 0.0f) + (v7 ? -hh2 : 0.0f);
        }

        float tux = ux + ux, tuy = uy + uy, twx = wx + wx, twy = wy + wy;
        float rtux = prcp(tux), rtuy = prcp(tuy), rtwx = prcp(twx), rtwy = prcp(twy);
        float dxe[4] = {-tux, -twx, tux, twx};
        float dye[4] = {-tuy, -twy, tuy, twy};
        float rdxe[4] = {-rtux, -rtwx, rtux, rtwx};
        float rdye[4] = {-rtuy, -rtwy, rtuy, rtwy};
        float r2w = prcp(hw2 + hw2), r2h = prcp(hh2 + hh2);

        // 16 intersections; exact reference semantics (incl. u-sign quirk), simplified in frame2
        float pvar[16];
#pragma unroll
        for (int e1 = 0; e1 < 4; e1++) {
            float x1 = fx[e1], y1 = fy[e1];
            {   // e2 = 0: Y = +hh2
                float tt = (hh2 - y1) * rdye[e1];
                float px = fmaf(tt, dxe[e1], x1);
                float uu = (hw2 - px) * (-r2w);
                bool mk = (tt > 0.0f) && (tt < 1.0f) && (uu > 0.0f) && (uu < 1.0f);
                pvar[e1 * 4 + 0] = px;
                float pxm = mk ? px : 0.0f, pym = mk ? hh2 : 0.0f;
                LDSV(8 + e1 * 4 + 0) = packh2(pxm, pym);
                sx += pxm; sy += pym;
                vm |= ((unsigned)mk) << (8 + e1 * 4 + 0);
            }
            {   // e2 = 1: X = -hw2
                float tt = (-hw2 - x1) * rdxe[e1];
                float py = fmaf(tt, dye[e1], y1);
                float uu = (hh2 - py) * (-r2h);
                bool mk = (tt > 0.0f) && (tt < 1.0f) && (uu > 0.0f) && (uu < 1.0f);
                pvar[e1 * 4 + 1] = py;
                float pxm = mk ? -hw2 : 0.0f, pym = mk ? py : 0.0f;
                LDSV(8 + e1 * 4 + 1) = packh2(pxm, pym);
                sx += pxm; sy += pym;
                vm |= ((unsigned)mk) << (8 + e1 * 4 + 1);
            }
            {   // e2 = 2: Y = -hh2
                float tt = (-hh2 - y1) * rdye[e1];
                float px = fmaf(tt, dxe[e1], x1);
                float uu = (-hw2 - px) * r2w;
                bool mk = (tt > 0.0f) && (tt < 1.0f) && (uu > 0.0f) && (uu < 1.0f);
                pvar[e1 * 4 + 2] = px;
                float pxm = mk ? px : 0.0f, pym = mk ? -hh2 : 0.0f;
                LDSV(8 + e1 * 4 + 2) = packh2(pxm, pym);
                sx += pxm; sy += pym;
                vm |= ((unsigned)mk) << (8 + e1 * 4 + 2);
            }
            {   // e2 = 3: X = +hw2
                float tt = (hw2 - x1) * rdxe[e1];
                float py = fmaf(tt, dye[e1], y1);
                float uu = (-hh2 - py) * r2h;
                bool mk = (tt > 0.0f) && (tt < 1.0f) && (uu > 0.0f) && (uu < 1.0f);
                pvar[e1 * 4 + 3] = py;
                float pxm = mk ? hw2 : 0.0f, pym = mk ? py : 0.0f;
                LDSV(8 + e1 * 4 + 3) = packh2(pxm, pym);
                sx += pxm; sy += pym;
                vm |= ((unsigned)mk) << (8 + e1 * 4 + 3);
            }
        }

        int nv = __popc(vm);
        float r0 = prcp(fmaxf((float)nv, 1.0f));
        float mx = sx * r0, my = sy * r0;

        unsigned ka[24];
#define MKKEY(K, XR, YR) do { \
        float xr_ = (XR), yr_ = (YR); \
        float d_ = fabsf(xr_) + fabsf(yr_); \
        float q_ = 1.0f - xr_ * prcp(d_); \
        float pa_ = copysignf(q_, yr_) + 4.0f; \
        unsigned key_ = (__float_as_uint(pa_) & 0xFFFFFFE0u) | (unsigned)(K); \
        ka[K] = ((vm >> (K)) & 1u) ? key_ : (0x7F000000u | (unsigned)(K)); \
    } while (0)
        float hpx = hw2 - mx, hmx = -hw2 - mx, hpy = hh2 - my, hmy = -hh2 - my;
#pragma unroll
        for (int k = 0; k < 4; k++) MKKEY(k, fx[k] - mx, fy[k] - my);
        MKKEY(4, hpx, hpy); MKKEY(5, hmx, hpy); MKKEY(6, hmx, hmy); MKKEY(7, hpx, hmy);
#pragma unroll
        for (int e1 = 0; e1 < 4; e1++) {
            MKKEY(8 + e1 * 4 + 0, pvar[e1 * 4 + 0] - mx, hpy);
            MKKEY(8 + e1 * 4 + 1, hmx, pvar[e1 * 4 + 1] - my);
            MKKEY(8 + e1 * 4 + 2, pvar[e1 * 4 + 2] - mx, hmy);
            MKKEY(8 + e1 * 4 + 3, hpx, pvar[e1 * 4 + 3] - my);
        }
#undef MKKEY

        // Batcher odd-even mergesort, n=24 (132 CEs), u32 min/max
#define CE(A, B) { unsigned lo_ = ka[A] < ka[B] ? ka[A] : ka[B]; \
                   unsigned hi_ = ka[A] < ka[B] ? ka[B] : ka[A]; \
                   ka[A] = lo_; ka[B] = hi_; }
        CE(0,1); CE(2,3); CE(4,5); CE(6,7); CE(8,9); CE(10,11); CE(12,13); CE(14,15); CE(16,17); CE(18,19); CE(20,21); CE(22,23);
        CE(0,2); CE(1,3); CE(4,6); CE(5,7); CE(8,10); CE(9,11); CE(12,14); CE(13,15); CE(16,18); CE(17,19); CE(20,22); CE(21,23);
        CE(1,2); CE(5,6); CE(9,10); CE(13,14); CE(17,18); CE(21,22);
        CE(0,4); CE(1,5); CE(2,6); CE(3,7); CE(8,12); CE(9,13); CE(10,14); CE(11,15); CE(16,20); CE(17,21); CE(18,22); CE(19,23);
        CE(2,4); CE(3,5); CE(10,12); CE(11,13); CE(18,20); CE(19,21);
        CE(1,2); CE(3,4); CE(5,6); CE(9,10); CE(11,12); CE(13,14); CE(17,18); CE(19,20); CE(21,22);
        CE(0,8); CE(1,9); CE(2,10); CE(3,11); CE(4,12); CE(5,13); CE(6,14); CE(7,15);
        CE(4,8); CE(5,9); CE(6,10); CE(7,11);
        CE(2,4); CE(3,5); CE(6,8); CE(7,9); CE(10,12); CE(11,13); CE(18,20); CE(19,21);
        CE(1,2); CE(3,4); CE(5,6); CE(7,8); CE(9,10); CE(11,12); CE(13,14); CE(17,18); CE(19,20); CE(21,22);
        CE(0,16); CE(1,17); CE(2,18); CE(3,19); CE(4,20); CE(5,21); CE(6,22); CE(7,23);
        CE(8,16); CE(9,17); CE(10,18); CE(11,19); CE(12,20); CE(13,21); CE(14,22); CE(15,23);
        CE(4,8); CE(5,9); CE(6,10); CE(7,11); CE(12,16); CE(13,17); CE(14,18); CE(15,19);
        CE(2,4); CE(3,5); CE(6,8); CE(7,9); CE(10,12); CE(11,13); CE(14,16); CE(15,17); CE(18,20); CE(19,21);
        CE(1,2); CE(3,4); CE(5,6); CE(7,8); CE(9,10); CE(11,12); CE(13,14); CE(15,16); CE(17,18); CE(19,20); CE(21,22);
#undef CE

        // gather sorted vertices (runtime slot -> LDS, conflict-free); ref-exact cyclic shoelace
        unsigned gu[24];
#pragma unroll
        for (int i = 0; i < 24; i++) gu[i] = ldsbuf[((ka[i] & 31u) << 7) + tid];
        float g0x, g0y;
        unpackh2(gu[0], g0x, g0y);
        float prevx = g0x, prevy = g0y;
        float area2 = 0.0f;
#pragma unroll
        for (int i = 1; i < 24; i++) {
            float xx, yy;
            unpackh2(gu[i], xx, yy);
            bool c = i < nv;
            float cxv = c ? xx : g0x;
            float cyv = c ? yy : g0y;
            area2 += prevx * cyv - cxv * prevy;
            prevx = cxv; prevy = cyv;
        }
        area2 += prevx * g0y - g0x * prevy;
        float inter2d = 0.5f * fabsf(area2);

        float inter3d = inter2d * zov;
        float uni = vol1 + vol2 - inter3d;
        float iou = inter3d / uni;
        loss = (1.0f - iou) * w;
    }
#undef LDSV

    // block reduction: wave shuffle + 2-wave LDS combine
#pragma unroll
    for (int off = 32; off > 0; off >>= 1) loss += __shfl_down(loss, off, 64);
    __shared__ float sm[THREADS / 64];
    int lane = threadIdx.x & 63, wv = threadIdx.x >> 6;
    if (lane == 0) sm[wv] = loss;
    __syncthreads();
    if (threadIdx.x == 0) {
        float s = 0.0f;
#pragma unroll
        for (int k = 0; k < THREADS / 64; k++) s += sm[k];
        partial[blockIdx.x] = s;
    }
}

__global__ void __launch_bounds__(1024) reduce_kernel(const float* __restrict__ partial,
                                                      int nb, float* __restrict__ out, int N) {
    float s = 0.0f;
    for (int i = threadIdx.x; i < nb; i += 1024) s += partial[i];
#pragma unroll
    for (int off = 32; off > 0; off >>= 1) s += __shfl_down(s, off, 64);
    __shared__ float sm[16];
    int lane = threadIdx.x & 63, wv = threadIdx.x >> 6;
    if (lane == 0) sm[wv] = s;
    __syncthreads();
    if (threadIdx.x == 0) {
        float tot = 0.0f;
#pragma unroll
        for (int k = 0; k < 16; k++) tot += sm[k];
        out[0] = tot / (float)N;
    }
}

extern "C" void kernel_launch(void* const* d_in, const int* in_sizes, int n_in,
                              void* d_out, int out_size, void* d_ws, size_t ws_size,
                              hipStream_t stream) {
    const float* pred = (const float*)d_in[0];
    const float* tgt  = (const float*)d_in[1];
    const float* wgt  = (const float*)d_in[2];
    int N = in_sizes[2];
    int nb = (N + THREADS - 1) / THREADS;
    float* partial = (float*)d_ws;
    iou3d_kernel<<<nb, THREADS, 0, stream>>>(pred, tgt, wgt, partial, N);
    reduce_kernel<<<1, 1024, 0, stream>>>(partial, nb, (float*)d_out, N);
}